// Round 7
// baseline (13409.645 us; speedup 1.0000x reference)
//
#include <hip/hip_runtime.h>
#include <hip/hip_bf16.h>
#include <cstdint>
#include <cstddef>

#define V_SZ 32000
#define E_SZ 512
#define U_SZ 1024
#define B_SZ 4
#define S_SZ 2048
#define GRU_WG 128   // 128 WGs x 256 thr = 512 waves; wave owns 2 h-columns

typedef _Float16 f16;
typedef _Float16 f16x2 __attribute__((ext_vector_type(2)));
typedef _Float16 f16x8 __attribute__((ext_vector_type(8)));
typedef _Float16 f16x4 __attribute__((ext_vector_type(4)));
typedef float    f32x4 __attribute__((ext_vector_type(4)));
typedef unsigned long long u64;

__device__ __forceinline__ void async_copy16(const void* g, void* l) {
  __builtin_amdgcn_global_load_lds(
      (const __attribute__((address_space(1))) void*)g,
      (__attribute__((address_space(3))) void*)l, 16, 0, 0);
}

__device__ __forceinline__ f32x4 mfma16(f16x8 a, f16x8 b, f32x4 c) {
  return __builtin_amdgcn_mfma_f32_16x16x32_f16(a, b, c, 0, 0, 0);
}

// full-wave (64) sum via DPP; result valid in lane 63 only. Pure VALU (no LDS pipe).
__device__ __forceinline__ float wave_sum64(float v) {
  v += __int_as_float(__builtin_amdgcn_update_dpp(0, __float_as_int(v), 0x111, 0xf, 0xf, true)); // row_shr:1
  v += __int_as_float(__builtin_amdgcn_update_dpp(0, __float_as_int(v), 0x112, 0xf, 0xf, true)); // row_shr:2
  v += __int_as_float(__builtin_amdgcn_update_dpp(0, __float_as_int(v), 0x114, 0xf, 0xf, true)); // row_shr:4
  v += __int_as_float(__builtin_amdgcn_update_dpp(0, __float_as_int(v), 0x118, 0xf, 0xf, true)); // row_shr:8
  v += __int_as_float(__builtin_amdgcn_update_dpp(0, __float_as_int(v), 0x142, 0xa, 0xf, true)); // row_bcast:15
  v += __int_as_float(__builtin_amdgcn_update_dpp(0, __float_as_int(v), 0x143, 0xc, 0xf, true)); // row_bcast:31
  return v;
}

// ---------------- embedding gather + hi/lo fp16 split ----------------
__global__ void k_gather_split(const int* __restrict__ inputs, const float* __restrict__ emb,
                               f16* __restrict__ x_hi, f16* __restrict__ x_lo) {
  int m = blockIdx.x;                  // 8192 rows, m = b*2048 + s
  int row = inputs[m];
  const float* src = emb + (size_t)row * E_SZ;
  int j = threadIdx.x * 4;
  f32x4 v = *(const f32x4*)(src + j);
  f16x4 hi, lo;
#pragma unroll
  for (int q = 0; q < 4; ++q) {
    f16 h = (f16)v[q];
    hi[q] = h;
    lo[q] = (f16)((v[q] - (float)h) * 4096.0f);
  }
  *(f16x4*)(x_hi + (size_t)m * E_SZ + j) = hi;
  *(f16x4*)(x_lo + (size_t)m * E_SZ + j) = lo;
}

// ---------------- transpose [K][N] fp32 -> [N][K] fp16 ----------------
__global__ void k_transpose_split(const float* __restrict__ W, f16* __restrict__ Wt,
                                  int K, int N) {
  __shared__ float tile[32][33];
  int tx = threadIdx.x & 31, ty = threadIdx.x >> 5;   // 32 x 8
  int n0 = blockIdx.x * 32, k0 = blockIdx.y * 32;
#pragma unroll
  for (int i = 0; i < 4; ++i)
    tile[ty + 8 * i][tx] = W[(size_t)(k0 + ty + 8 * i) * N + n0 + tx];
  __syncthreads();
#pragma unroll
  for (int i = 0; i < 4; ++i)
    Wt[(size_t)(n0 + ty + 8 * i) * K + k0 + tx] = (f16)tile[tx][ty + 8 * i];
}

// ---------------- fp16 2-pass GEMM: C = (Ah + Al/4096) @ Bt^T + bias ----------------
template<int K, bool REMAP>
__global__ __launch_bounds__(256, 2)
void k_gemm2s(const f16* __restrict__ Ah, const f16* __restrict__ Al,
              const f16* __restrict__ Bt, const float* __restrict__ bias,
              float* __restrict__ C, int N) {
  __shared__ f16 lds[2][3 * 4096];     // 3 tiles x 512 granules x 8 halves, 24KB/buf
  const int tid = threadIdx.x;
  const int lane = tid & 63;
  const int wave = tid >> 6;
  const int wm = wave >> 1, wn = wave & 1;
  const int m0 = blockIdx.y * 128;
  const int n0 = blockIdx.x * 128;

  auto stage = [&](int buf, int kk) {
#pragma unroll
    for (int i = 0; i < 6; ++i) {
      int g = i * 256 + tid;           // 1536 granules: [0,512)=Ah [512,1024)=Al [1024,1536)=B
      int tile = g >> 9;
      int idx = g & 511;
      int r = idx >> 2;
      int kg = (idx & 3) ^ ((r >> 1) & 3);   // inverse-swizzled source
      const f16* src = (tile == 0) ? Ah : (tile == 1) ? Al : Bt;
      int row = (tile == 2) ? (n0 + r) : (m0 + r);
      const f16* gp = src + (size_t)row * K + kk + kg * 8;
      f16* lp = &lds[buf][(g & ~63) * 8];     // wave-uniform base; HW adds lane*16B
      async_copy16(gp, lp);
    }
  };

  f32x4 accH[4][4] = {};
  f32x4 accL[4][4] = {};

  stage(0, 0);
  int buf = 0;
  for (int kk = 0; kk < K; kk += 32) {
    __syncthreads();                   // drains vmcnt -> buf ready, prev compute done
    if (kk + 32 < K) stage(buf ^ 1, kk + 32);
    const f16* base = &lds[buf][0];
    const int kg = lane >> 4;
    f16x8 bfr[4];
#pragma unroll
    for (int fn = 0; fn < 4; ++fn) {
      int r = wn * 64 + fn * 16 + (lane & 15);
      bfr[fn] = *(const f16x8*)(base + 2 * 4096 + r * 32 + ((kg ^ ((r >> 1) & 3)) * 8));
    }
#pragma unroll
    for (int fm = 0; fm < 4; ++fm) {
      int r = wm * 64 + fm * 16 + (lane & 15);
      int off = r * 32 + ((kg ^ ((r >> 1) & 3)) * 8);
      f16x8 ah = *(const f16x8*)(base + off);
      f16x8 al = *(const f16x8*)(base + 4096 + off);
#pragma unroll
      for (int fn = 0; fn < 4; ++fn) {
        accH[fm][fn] = mfma16(ah, bfr[fn], accH[fm][fn]);
        accL[fm][fn] = mfma16(al, bfr[fn], accL[fm][fn]);
      }
    }
    buf ^= 1;
  }

  const float inv = 1.0f / 4096.0f;
#pragma unroll
  for (int fn = 0; fn < 4; ++fn) {
    int col = n0 + wn * 64 + fn * 16 + (lane & 15);
    float bv = bias[col];
#pragma unroll
    for (int fm = 0; fm < 4; ++fm) {
      int row0 = m0 + wm * 64 + fm * 16 + ((lane >> 4) << 2);
#pragma unroll
      for (int j = 0; j < 4; ++j) {
        int row = row0 + j;
        float v = accH[fm][fn][j] + inv * accL[fm][fn][j] + bv;
        size_t orow = REMAP ? ((size_t)(row & (S_SZ - 1)) * B_SZ + (row >> 11))
                            : (size_t)row;
        C[orow * (size_t)N + col] = v;
      }
    }
  }
}

// ---------------- persistent GRU recurrence (v7: phase-tag + depth-2 poll pipe) ---
// 512 waves; wave owns cols {2W,2W+1}, all 3 gates. b=0..3 staggered sub-slices.
// Protocol: ring[8][b][1024] fp32. NO poison. Each published fp32 carries a PHASE
// TAG in its mantissa LSB: tag(t) = (t>>3)&1 (slot t&7 reuses every 8 steps with
// the tag flipped -> stale data self-identifies; LSB distortion 2^-24, negligible;
// |h|<1 so no special values). Per-pair atomicity from the single 8B atomic store;
// checking one LSB per u64 suffices. Init: slot0 = zeros (tag 0 = expected at t=0),
// slots 1-7 = 0xFF (LSB 1 = wrong tag until first publish).
// Schedule per slice: wait q[b] (issued 2 slices ago -> latency hidden) -> dots ->
// DPP reduce -> ISSUE q[(b+2)&3] polls + xg prefetch (BEFORE stores: vmcnt retires
// in order, so putting loads first keeps store acks off the next waits) ->
// sched_barrier pins issue point -> lane63 gates + tag-forced publish + hs stores
// (acks ride in background; nothing ever waits vmcnt(0) on the hot path).
__global__ __launch_bounds__(256, 1)
void k_gru(const float* __restrict__ xg, const float* __restrict__ Wh,
           const float* __restrict__ bh, u64* __restrict__ h_ring,
           f16* __restrict__ hs_hi, f16* __restrict__ hs_lo) {
  __shared__ float Whs[8][1028];       // staging only (init), 32.9 KB

  const int tid = threadIdx.x;
  const int lane = tid & 63;
  const int wave = tid >> 6;
  const int u0 = blockIdx.x * 8;       // WG's 8 cols
  const int col0 = u0 + wave * 2;      // this wave's first col

  // ---- stage Wh into registers: Wreg order [z0,z1,r0,r1,h0,h1] ----
  f32x4 Wreg[6][4];                    // Wreg[c][i] = Wh[k=i*256+lane*4 ..+3][col]
  for (int gate = 0; gate < 3; ++gate) {
    __syncthreads();
    for (int idx = tid; idx < 8 * 1024; idx += 256) {
      int j = idx & 7, k = idx >> 3;
      Whs[j][k] = Wh[(size_t)k * 3072 + gate * 1024 + u0 + j];
    }
    __syncthreads();
#pragma unroll
    for (int cj = 0; cj < 2; ++cj)
#pragma unroll
      for (int i = 0; i < 4; ++i)
        Wreg[gate * 2 + cj][i] = *(const f32x4*)&Whs[wave * 2 + cj][i * 256 + lane * 4];
  }

  const float bz0 = bh[col0],        bz1 = bh[col0 + 1];
  const float br0 = bh[1024 + col0], br1 = bh[1024 + col0 + 1];
  const float bq0 = bh[2048 + col0], bq1 = bh[2048 + col0 + 1];
  float hold0[4] = {0.f, 0.f, 0.f, 0.f};
  float hold1[4] = {0.f, 0.f, 0.f, 0.f};

  u64 q[4][8];                         // 4 static poll sets (b fully unrolled ->
  float2 xzv[4], xrv[4], xhv[4];       //  constant indices everywhere; rule #20 safe)

  auto pollIssue = [&](u64 (&qs)[8], int slot, int row) {
    const u64* base = h_ring + ((size_t)slot * B_SZ + row) * 512 + 2 * lane;
#pragma unroll
    for (int i = 0; i < 4; ++i) {
      qs[2 * i]     = __hip_atomic_load(base + i * 128,
                                        __ATOMIC_RELAXED, __HIP_MEMORY_SCOPE_AGENT);
      qs[2 * i + 1] = __hip_atomic_load(base + i * 128 + 1,
                                        __ATOMIC_RELAXED, __HIP_MEMORY_SCOPE_AGENT);
    }
  };
  auto xgIssue = [&](int b2, int t2) {
    const float* p = xg + ((size_t)t2 * B_SZ + b2) * 3072 + col0;
    xzv[b2] = *(const float2*)p;
    xrv[b2] = *(const float2*)(p + 1024);
    xhv[b2] = *(const float2*)(p + 2048);
  };

  // bootstrap: polls + xg for slices (0,0) and (0,1)
  pollIssue(q[0], 0, 0);
  pollIssue(q[1], 0, 1);
  xgIssue(0, 0);
  xgIssue(1, 0);

  for (int t = 0; t < S_SZ; ++t) {
    const unsigned tagExp = (unsigned)((t >> 3) & 1);
    const unsigned tagPub = (unsigned)(((t + 1) >> 3) & 1);
#pragma unroll
    for (int b = 0; b < 4; ++b) {
      const int b2 = (b + 2) & 3;            // slice+2 batch row
      int t2 = t + (b >> 1);                 // slice+2 time (b=0,1 -> t; b=2,3 -> t+1)
      if (t2 >= S_SZ) t2 = S_SZ - 1;         // tail clamp (values never consumed)

      // ---- wait on q[b] (prefetched 2 slices ago); tag check = 1 LSB per u64 ----
      while (true) {
        bool ok = true;
#pragma unroll
        for (int i = 0; i < 8; ++i)
          ok = ok && (((unsigned)q[b][i] & 1u) == tagExp);
        if (__all(ok)) break;
        __builtin_amdgcn_s_sleep(1);
        pollIssue(q[b], t & 7, b);           // rare path: reissue (drains stores, ok)
      }

      // ---- 6 dots over this lane's 16 k-values (96 FMA; halves of q are free) ----
      float a6[6];
#pragma unroll
      for (int c = 0; c < 6; ++c) {
        float v = 0.0f;
#pragma unroll
        for (int i = 0; i < 8; ++i) {
          v += Wreg[c][i >> 1][2 * (i & 1)]     * __uint_as_float((unsigned)q[b][i]);
          v += Wreg[c][i >> 1][2 * (i & 1) + 1] * __uint_as_float((unsigned)(q[b][i] >> 32));
        }
        a6[c] = v;
      }
      float s0 = wave_sum64(a6[0]), s1 = wave_sum64(a6[1]), s2 = wave_sum64(a6[2]);
      float s3 = wave_sum64(a6[3]), s4 = wave_sum64(a6[4]), s5 = wave_sum64(a6[5]);

      // ---- issue slice+2 polls and xg prefetch BEFORE any stores ----
      pollIssue(q[b2], t2 & 7, b2);
      xgIssue(b2, t2);
      __builtin_amdgcn_sched_barrier(0);     // pin issue point (no sinking to use)

      // ---- lane63: gates, tag-forced publish, hs output ----
      if (lane == 63) {
        const float2 xz = xzv[b], xr = xrv[b], xh = xhv[b];
        float z0 = __builtin_amdgcn_rcpf(1.0f + __expf(-(xz.x + s0 + bz0)));
        float z1 = __builtin_amdgcn_rcpf(1.0f + __expf(-(xz.y + s1 + bz1)));
        float r0 = __builtin_amdgcn_rcpf(1.0f + __expf(-(xr.x + s2 + br0)));
        float r1 = __builtin_amdgcn_rcpf(1.0f + __expf(-(xr.y + s3 + br1)));
        float a0 = xh.x + r0 * (s4 + bq0);
        float a1 = xh.y + r1 * (s5 + bq1);
        float e0 = __expf(-2.0f * fabsf(a0));
        float e1 = __expf(-2.0f * fabsf(a1));
        float hc0 = copysignf((1.0f - e0) * __builtin_amdgcn_rcpf(1.0f + e0), a0);
        float hc1 = copysignf((1.0f - e1) * __builtin_amdgcn_rcpf(1.0f + e1), a1);
        float h0 = z0 * hold0[b] + (1.0f - z0) * hc0;
        float h1 = z1 * hold1[b] + (1.0f - z1) * hc1;
        // force mantissa LSB = phase tag (2^-24 distortion; producer uses same value)
        unsigned u0b = (__float_as_uint(h0) & ~1u) | tagPub;
        unsigned u1b = (__float_as_uint(h1) & ~1u) | tagPub;
        float h0f = __uint_as_float(u0b);
        float h1f = __uint_as_float(u1b);
        hold0[b] = h0f; hold1[b] = h1f;
        u64 hv = ((u64)u1b << 32) | (u64)u0b;
        __hip_atomic_store(h_ring + ((size_t)((t + 1) & 7) * B_SZ + b) * 512 + (col0 >> 1),
                           hv, __ATOMIC_RELAXED, __HIP_MEMORY_SCOPE_AGENT);
        // hs output (plain cached stores; visible at kernel end)
        size_t hidx = ((size_t)b * S_SZ + t) * U_SZ + col0;
        f16 h0h = (f16)h0f, h1h = (f16)h1f;
        f16x2 hi2; hi2[0] = h0h; hi2[1] = h1h;
        *(f16x2*)(hs_hi + hidx) = hi2;
        f16x2 lo2;
        lo2[0] = (f16)((h0f - (float)h0h) * 4096.0f);
        lo2[1] = (f16)((h1f - (float)h1h) * 4096.0f);
        *(f16x2*)(hs_lo + hidx) = lo2;
      }
    }
  }
}

// ---------------- launch ----------------
extern "C" void kernel_launch(void* const* d_in, const int* in_sizes, int n_in,
                              void* d_out, int out_size, void* d_ws, size_t ws_size,
                              hipStream_t stream) {
  const int*   inputs = (const int*)d_in[0];
  const float* emb    = (const float*)d_in[1];
  const float* Wx     = (const float*)d_in[2];
  const float* Wh     = (const float*)d_in[3];
  const float* bx     = (const float*)d_in[4];
  const float* bh     = (const float*)d_in[5];
  const float* Wd     = (const float*)d_in[6];
  const float* bd     = (const float*)d_in[7];
  float* out = (float*)d_out;

  char* ws = (char*)d_ws;
  // layout (bytes), all 256-aligned
  f16*   x_hi  = (f16*)(ws + 0);            //  8,388,608
  f16*   x_lo  = (f16*)(ws + 8388608);      //  8,388,608
  f16*   Wx_t  = (f16*)(ws + 16777216);     //  3,145,728  [3072][512]
  f16*   Wd_t  = (f16*)(ws + 19922944);     // 65,536,000  [32000][1024]
  f16*   hs_hi = (f16*)(ws + 85458944);     // 16,777,216  [B*S][1024]
  f16*   hs_lo = (f16*)(ws + 102236160);    // 16,777,216
  float* xg    = (float*)(ws + 119013376);  // 100,663,296 [S][B][3072]
  u64*   h_ring = (u64*)(ws + 219676672);   // 131,072     [8][4][1024] fp32

  // ring init every call (graph-replay safe): slot0 = S_0 = zeros (tag 0), slots
  // 1-7 = 0xFF (LSB 1 = wrong tag until first publish of that slot)
  hipMemsetAsync(ws + 219676672, 0x00, 16384, stream);
  hipMemsetAsync(ws + 219676672 + 16384, 0xFF, 114688, stream);

  k_gather_split<<<B_SZ * S_SZ, 128, 0, stream>>>(inputs, emb, x_hi, x_lo);
  k_transpose_split<<<dim3(3072 / 32, 512 / 32), 256, 0, stream>>>(Wx, Wx_t, 512, 3072);
  k_transpose_split<<<dim3(V_SZ / 32, 1024 / 32), 256, 0, stream>>>(Wd, Wd_t, 1024, V_SZ);
  k_gemm2s<512, true><<<dim3(3072 / 128, 8192 / 128), 256, 0, stream>>>(
      x_hi, x_lo, Wx_t, bx, xg, 3072);
  k_gru<<<GRU_WG, 256, 0, stream>>>(xg, Wh, bh, h_ring, hs_hi, hs_lo);
  k_gemm2s<1024, false><<<dim3(V_SZ / 128, 8192 / 128), 256, 0, stream>>>(
      hs_hi, hs_lo, Wd_t, bd, out, V_SZ);
}

// Round 8
// 11149.097 us; speedup vs baseline: 1.2028x; 1.2028x over previous
//
#include <hip/hip_runtime.h>
#include <hip/hip_bf16.h>
#include <cstdint>
#include <cstddef>

#define V_SZ 32000
#define E_SZ 512
#define U_SZ 1024
#define B_SZ 4
#define S_SZ 2048
#define GRU_WG 128   // 128 WGs x 256 thr = 512 waves; wave owns 2 h-columns

typedef _Float16 f16;
typedef _Float16 f16x2 __attribute__((ext_vector_type(2)));
typedef _Float16 f16x8 __attribute__((ext_vector_type(8)));
typedef _Float16 f16x4 __attribute__((ext_vector_type(4)));
typedef float    f32x4 __attribute__((ext_vector_type(4)));
typedef unsigned long long u64;

__device__ __forceinline__ void async_copy16(const void* g, void* l) {
  __builtin_amdgcn_global_load_lds(
      (const __attribute__((address_space(1))) void*)g,
      (__attribute__((address_space(3))) void*)l, 16, 0, 0);
}

__device__ __forceinline__ f32x4 mfma16(f16x8 a, f16x8 b, f32x4 c) {
  return __builtin_amdgcn_mfma_f32_16x16x32_f16(a, b, c, 0, 0, 0);
}

// full-wave (64) sum via DPP; result valid in lane 63 only. Pure VALU (no LDS pipe).
__device__ __forceinline__ float wave_sum64(float v) {
  v += __int_as_float(__builtin_amdgcn_update_dpp(0, __float_as_int(v), 0x111, 0xf, 0xf, true)); // row_shr:1
  v += __int_as_float(__builtin_amdgcn_update_dpp(0, __float_as_int(v), 0x112, 0xf, 0xf, true)); // row_shr:2
  v += __int_as_float(__builtin_amdgcn_update_dpp(0, __float_as_int(v), 0x114, 0xf, 0xf, true)); // row_shr:4
  v += __int_as_float(__builtin_amdgcn_update_dpp(0, __float_as_int(v), 0x118, 0xf, 0xf, true)); // row_shr:8
  v += __int_as_float(__builtin_amdgcn_update_dpp(0, __float_as_int(v), 0x142, 0xa, 0xf, true)); // row_bcast:15
  v += __int_as_float(__builtin_amdgcn_update_dpp(0, __float_as_int(v), 0x143, 0xc, 0xf, true)); // row_bcast:31
  return v;
}

// ---------------- embedding gather + hi/lo fp16 split ----------------
__global__ void k_gather_split(const int* __restrict__ inputs, const float* __restrict__ emb,
                               f16* __restrict__ x_hi, f16* __restrict__ x_lo) {
  int m = blockIdx.x;                  // 8192 rows, m = b*2048 + s
  int row = inputs[m];
  const float* src = emb + (size_t)row * E_SZ;
  int j = threadIdx.x * 4;
  f32x4 v = *(const f32x4*)(src + j);
  f16x4 hi, lo;
#pragma unroll
  for (int q = 0; q < 4; ++q) {
    f16 h = (f16)v[q];
    hi[q] = h;
    lo[q] = (f16)((v[q] - (float)h) * 4096.0f);
  }
  *(f16x4*)(x_hi + (size_t)m * E_SZ + j) = hi;
  *(f16x4*)(x_lo + (size_t)m * E_SZ + j) = lo;
}

// ---------------- transpose [K][N] fp32 -> [N][K] fp16 ----------------
__global__ void k_transpose_split(const float* __restrict__ W, f16* __restrict__ Wt,
                                  int K, int N) {
  __shared__ float tile[32][33];
  int tx = threadIdx.x & 31, ty = threadIdx.x >> 5;   // 32 x 8
  int n0 = blockIdx.x * 32, k0 = blockIdx.y * 32;
#pragma unroll
  for (int i = 0; i < 4; ++i)
    tile[ty + 8 * i][tx] = W[(size_t)(k0 + ty + 8 * i) * N + n0 + tx];
  __syncthreads();
#pragma unroll
  for (int i = 0; i < 4; ++i)
    Wt[(size_t)(n0 + ty + 8 * i) * K + k0 + tx] = (f16)tile[tx][ty + 8 * i];
}

// ---------------- fp16 2-pass GEMM: C = (Ah + Al/4096) @ Bt^T + bias ----------------
template<int K, bool REMAP>
__global__ __launch_bounds__(256, 2)
void k_gemm2s(const f16* __restrict__ Ah, const f16* __restrict__ Al,
              const f16* __restrict__ Bt, const float* __restrict__ bias,
              float* __restrict__ C, int N) {
  __shared__ f16 lds[2][3 * 4096];     // 3 tiles x 512 granules x 8 halves, 24KB/buf
  const int tid = threadIdx.x;
  const int lane = tid & 63;
  const int wave = tid >> 6;
  const int wm = wave >> 1, wn = wave & 1;
  const int m0 = blockIdx.y * 128;
  const int n0 = blockIdx.x * 128;

  auto stage = [&](int buf, int kk) {
#pragma unroll
    for (int i = 0; i < 6; ++i) {
      int g = i * 256 + tid;           // 1536 granules: [0,512)=Ah [512,1024)=Al [1024,1536)=B
      int tile = g >> 9;
      int idx = g & 511;
      int r = idx >> 2;
      int kg = (idx & 3) ^ ((r >> 1) & 3);   // inverse-swizzled source
      const f16* src = (tile == 0) ? Ah : (tile == 1) ? Al : Bt;
      int row = (tile == 2) ? (n0 + r) : (m0 + r);
      const f16* gp = src + (size_t)row * K + kk + kg * 8;
      f16* lp = &lds[buf][(g & ~63) * 8];     // wave-uniform base; HW adds lane*16B
      async_copy16(gp, lp);
    }
  };

  f32x4 accH[4][4] = {};
  f32x4 accL[4][4] = {};

  stage(0, 0);
  int buf = 0;
  for (int kk = 0; kk < K; kk += 32) {
    __syncthreads();                   // drains vmcnt -> buf ready, prev compute done
    if (kk + 32 < K) stage(buf ^ 1, kk + 32);
    const f16* base = &lds[buf][0];
    const int kg = lane >> 4;
    f16x8 bfr[4];
#pragma unroll
    for (int fn = 0; fn < 4; ++fn) {
      int r = wn * 64 + fn * 16 + (lane & 15);
      bfr[fn] = *(const f16x8*)(base + 2 * 4096 + r * 32 + ((kg ^ ((r >> 1) & 3)) * 8));
    }
#pragma unroll
    for (int fm = 0; fm < 4; ++fm) {
      int r = wm * 64 + fm * 16 + (lane & 15);
      int off = r * 32 + ((kg ^ ((r >> 1) & 3)) * 8);
      f16x8 ah = *(const f16x8*)(base + off);
      f16x8 al = *(const f16x8*)(base + 4096 + off);
#pragma unroll
      for (int fn = 0; fn < 4; ++fn) {
        accH[fm][fn] = mfma16(ah, bfr[fn], accH[fm][fn]);
        accL[fm][fn] = mfma16(al, bfr[fn], accL[fm][fn]);
      }
    }
    buf ^= 1;
  }

  const float inv = 1.0f / 4096.0f;
#pragma unroll
  for (int fn = 0; fn < 4; ++fn) {
    int col = n0 + wn * 64 + fn * 16 + (lane & 15);
    float bv = bias[col];
#pragma unroll
    for (int fm = 0; fm < 4; ++fm) {
      int row0 = m0 + wm * 64 + fm * 16 + ((lane >> 4) << 2);
#pragma unroll
      for (int j = 0; j < 4; ++j) {
        int row = row0 + j;
        float v = accH[fm][fn][j] + inv * accL[fm][fn][j] + bv;
        size_t orow = REMAP ? ((size_t)(row & (S_SZ - 1)) * B_SZ + (row >> 11))
                            : (size_t)row;
        C[orow * (size_t)N + col] = v;
      }
    }
  }
}

// ---------------- persistent GRU recurrence (v8: v6 protocol + drain hygiene) -----
// v6's poison ring protocol EXACTLY (depth 8, poison distance 4, relaxed agent
// atomics, per-batch hold). Three scheduling changes, all targeting the per-slice
// vmcnt drain identified in rounds 6/7:
//  (1) poison check PEELED out of the retry loop -> the common-case wait is a
//      straight-line counted vmcnt (younger ops statically known), not the
//      loop-merge vmcnt(0) that drained store-acks + fresh xg loads every slice.
//  (2) polls + xg issued BEFORE lane63's stores (memory-fenced): in-order vmcnt
//      retirement => waiting on polls never waits on the same slice's stores;
//      acks ride >=2 slices in background. Poison safety: poison@(t,b) retires by
//      the wait of slice (t,b+2) (its polls were issued after those stores), 10
//      sub-slices before the same-address publish@(t+3,b).
//  (3) xg prefetched 1 full step (4 slices) ahead into b-indexed static arrays ->
//      its ~900cy HBM latency is fully aged before any wait could expose it.
__global__ __launch_bounds__(256, 1)
void k_gru(const float* __restrict__ xg, const float* __restrict__ Wh,
           const float* __restrict__ bh, u64* __restrict__ h_ring,
           f16* __restrict__ hs_hi, f16* __restrict__ hs_lo) {
  __shared__ float Whs[8][1028];       // staging only (init), 32.9 KB

  const int tid = threadIdx.x;
  const int lane = tid & 63;
  const int wave = tid >> 6;
  const int u0 = blockIdx.x * 8;       // WG's 8 cols
  const int col0 = u0 + wave * 2;      // this wave's first col

  // ---- stage Wh into registers: Wreg order [z0,z1,r0,r1,h0,h1] ----
  f32x4 Wreg[6][4];                    // Wreg[c][i] = Wh[k=i*256+lane*4 ..+3][col]
  for (int gate = 0; gate < 3; ++gate) {
    __syncthreads();
    for (int idx = tid; idx < 8 * 1024; idx += 256) {
      int j = idx & 7, k = idx >> 3;
      Whs[j][k] = Wh[(size_t)k * 3072 + gate * 1024 + u0 + j];
    }
    __syncthreads();
#pragma unroll
    for (int cj = 0; cj < 2; ++cj)
#pragma unroll
      for (int i = 0; i < 4; ++i)
        Wreg[gate * 2 + cj][i] = *(const f32x4*)&Whs[wave * 2 + cj][i * 256 + lane * 4];
  }

  const float bz0 = bh[col0],        bz1 = bh[col0 + 1];
  const float br0 = bh[1024 + col0], br1 = bh[1024 + col0 + 1];
  const float bq0 = bh[2048 + col0], bq1 = bh[2048 + col0 + 1];
  float hold0[4] = {0.f, 0.f, 0.f, 0.f};
  float hold1[4] = {0.f, 0.f, 0.f, 0.f};
  const u64 POIS = 0xFFFFFFFFFFFFFFFFull;

  u64 q[8];                            // this lane's 16 h floats as 8 u64 chunks
  const u64* pbase;                    // current poll base (slot,row)
  auto pollLoads = [&]() {
#pragma unroll
    for (int i = 0; i < 4; ++i) {
      q[2 * i]     = __hip_atomic_load(pbase + i * 128 + 2 * lane,
                                       __ATOMIC_RELAXED, __HIP_MEMORY_SCOPE_AGENT);
      q[2 * i + 1] = __hip_atomic_load(pbase + i * 128 + 2 * lane + 1,
                                       __ATOMIC_RELAXED, __HIP_MEMORY_SCOPE_AGENT);
    }
  };
  auto issue = [&](int slot, int row) {
    pbase = h_ring + ((size_t)slot * B_SZ + row) * 512;
    pollLoads();
  };

  // xg prefetch state: one step of lookahead per batch row (static, b-unrolled)
  float2 xzv[4], xrv[4], xhv[4];
  auto xgIssue = [&](int b2, int t2) {
    const float* p = xg + ((size_t)t2 * B_SZ + b2) * 3072 + col0;
    xzv[b2] = *(const float2*)p;
    xrv[b2] = *(const float2*)(p + 1024);
    xhv[b2] = *(const float2*)(p + 2048);
  };

  // bootstrap: poll (t=0,b=0) = slot 0 (zeros); xg for all 4 slices of step 0
  issue(0, 0);
  xgIssue(0, 0); xgIssue(1, 0); xgIssue(2, 0); xgIssue(3, 0);

  for (int t = 0; t < S_SZ; ++t) {
#pragma unroll
    for (int b = 0; b < 4; ++b) {
      // local copy of this slice's xg (prefetched 4 slices ago) before overwrite
      const float2 xz = xzv[b], xr = xrv[b], xh = xhv[b];

      // ---- peeled fast-path check: counted wait on prefetched polls ----
      {
        bool ok = (q[0] != POIS) && (q[1] != POIS) && (q[2] != POIS) && (q[3] != POIS)
               && (q[4] != POIS) && (q[5] != POIS) && (q[6] != POIS) && (q[7] != POIS);
        if (!__all(ok)) {
          while (true) {                       // rare path: full re-poll + drain
            __builtin_amdgcn_s_sleep(1);
            pollLoads();
            bool ok2 = (q[0] != POIS) && (q[1] != POIS) && (q[2] != POIS) && (q[3] != POIS)
                    && (q[4] != POIS) && (q[5] != POIS) && (q[6] != POIS) && (q[7] != POIS);
            if (__all(ok2)) break;
          }
        }
      }
      // unpack chunks -> 16 floats (register reinterpretation, no VALU cost)
      float hp[16];
#pragma unroll
      for (int j2 = 0; j2 < 8; ++j2) {
        hp[2 * j2]     = __uint_as_float((unsigned int)q[j2]);
        hp[2 * j2 + 1] = __uint_as_float((unsigned int)(q[j2] >> 32));
      }
      // 6 dots over this lane's 16 k-values (96 FMA)
      float a6[6];
#pragma unroll
      for (int c = 0; c < 6; ++c) {
        float v = 0.0f;
#pragma unroll
        for (int i = 0; i < 4; ++i)
#pragma unroll
          for (int qq = 0; qq < 4; ++qq)
            v += Wreg[c][i][qq] * hp[4 * i + qq];
        a6[c] = v;
      }
      float s0 = wave_sum64(a6[0]), s1 = wave_sum64(a6[1]), s2 = wave_sum64(a6[2]);
      float s3 = wave_sum64(a6[3]), s4 = wave_sum64(a6[4]), s5 = wave_sum64(a6[5]);

      // ---- issue next-slice polls + next-step xg BEFORE any stores ----
      asm volatile("" ::: "memory");
      {
        const int nb = (b + 1) & 3;
        const int nt = (b == 3) ? (t + 1) : t;
        issue(nt & 7, nb);                     // polls for slice+1 (1-slice lookahead)
        const int tp1 = (t + 1 < S_SZ) ? (t + 1) : (S_SZ - 1);  // clamp (tail unused)
        xgIssue(b, tp1);                       // xg for (t+1, b): 4-slice lookahead
      }
      asm volatile("" ::: "memory");

      // ---- lane63: poison + gates + publish + hs output (acks ride in background) ----
      if (lane == 63) {
        // poison own pair of slot (t+4)&7 (held h[b](t-4); all readers provably past)
        __hip_atomic_store(h_ring + ((size_t)((t + 4) & 7) * B_SZ + b) * 512 + (col0 >> 1),
                           POIS, __ATOMIC_RELAXED, __HIP_MEMORY_SCOPE_AGENT);
        float z0 = __builtin_amdgcn_rcpf(1.0f + __expf(-(xz.x + s0 + bz0)));
        float z1 = __builtin_amdgcn_rcpf(1.0f + __expf(-(xz.y + s1 + bz1)));
        float r0 = __builtin_amdgcn_rcpf(1.0f + __expf(-(xr.x + s2 + br0)));
        float r1 = __builtin_amdgcn_rcpf(1.0f + __expf(-(xr.y + s3 + br1)));
        float a0 = xh.x + r0 * (s4 + bq0);
        float a1 = xh.y + r1 * (s5 + bq1);
        float e0 = __expf(-2.0f * fabsf(a0));
        float e1 = __expf(-2.0f * fabsf(a1));
        float hc0 = copysignf((1.0f - e0) * __builtin_amdgcn_rcpf(1.0f + e0), a0);
        float hc1 = copysignf((1.0f - e1) * __builtin_amdgcn_rcpf(1.0f + e1), a1);
        float h0 = z0 * hold0[b] + (1.0f - z0) * hc0;
        float h1 = z1 * hold1[b] + (1.0f - z1) * hc1;
        hold0[b] = h0; hold1[b] = h1;
        // publish pair to slot (t+1)&7 (data IS flag; 8B atomic store)
        u64 hv = ((u64)__float_as_uint(h1) << 32) | (u64)__float_as_uint(h0);
        __hip_atomic_store(h_ring + ((size_t)((t + 1) & 7) * B_SZ + b) * 512 + (col0 >> 1),
                           hv, __ATOMIC_RELAXED, __HIP_MEMORY_SCOPE_AGENT);
        // hs output (plain cached stores; visible at kernel end)
        size_t hidx = ((size_t)b * S_SZ + t) * U_SZ + col0;
        f16 h0h = (f16)h0, h1h = (f16)h1;
        f16x2 hi2; hi2[0] = h0h; hi2[1] = h1h;
        *(f16x2*)(hs_hi + hidx) = hi2;
        f16x2 lo2;
        lo2[0] = (f16)((h0 - (float)h0h) * 4096.0f);
        lo2[1] = (f16)((h1 - (float)h1h) * 4096.0f);
        *(f16x2*)(hs_lo + hidx) = lo2;
      }
    }
  }
}

// ---------------- launch ----------------
extern "C" void kernel_launch(void* const* d_in, const int* in_sizes, int n_in,
                              void* d_out, int out_size, void* d_ws, size_t ws_size,
                              hipStream_t stream) {
  const int*   inputs = (const int*)d_in[0];
  const float* emb    = (const float*)d_in[1];
  const float* Wx     = (const float*)d_in[2];
  const float* Wh     = (const float*)d_in[3];
  const float* bx     = (const float*)d_in[4];
  const float* bh     = (const float*)d_in[5];
  const float* Wd     = (const float*)d_in[6];
  const float* bd     = (const float*)d_in[7];
  float* out = (float*)d_out;

  char* ws = (char*)d_ws;
  // layout (bytes), all 256-aligned
  f16*   x_hi  = (f16*)(ws + 0);            //  8,388,608
  f16*   x_lo  = (f16*)(ws + 8388608);      //  8,388,608
  f16*   Wx_t  = (f16*)(ws + 16777216);     //  3,145,728  [3072][512]
  f16*   Wd_t  = (f16*)(ws + 19922944);     // 65,536,000  [32000][1024]
  f16*   hs_hi = (f16*)(ws + 85458944);     // 16,777,216  [B*S][1024]
  f16*   hs_lo = (f16*)(ws + 102236160);    // 16,777,216
  float* xg    = (float*)(ws + 119013376);  // 100,663,296 [S][B][3072]
  u64*   h_ring = (u64*)(ws + 219676672);   // 131,072     [8][4][1024] fp32

  // ring init every call (graph-replay safe): slot0 = S_0 = zeros, slots 1-7 = -NaN
  hipMemsetAsync(ws + 219676672, 0x00, 16384, stream);
  hipMemsetAsync(ws + 219676672 + 16384, 0xFF, 114688, stream);

  k_gather_split<<<B_SZ * S_SZ, 128, 0, stream>>>(inputs, emb, x_hi, x_lo);
  k_transpose_split<<<dim3(3072 / 32, 512 / 32), 256, 0, stream>>>(Wx, Wx_t, 512, 3072);
  k_transpose_split<<<dim3(V_SZ / 32, 1024 / 32), 256, 0, stream>>>(Wd, Wd_t, 1024, V_SZ);
  k_gemm2s<512, true><<<dim3(3072 / 128, 8192 / 128), 256, 0, stream>>>(
      x_hi, x_lo, Wx_t, bx, xg, 3072);
  k_gru<<<GRU_WG, 256, 0, stream>>>(xg, Wh, bh, h_ring, hs_hi, hs_lo);
  k_gemm2s<1024, false><<<dim3(V_SZ / 128, 8192 / 128), 256, 0, stream>>>(
      hs_hi, hs_lo, Wd_t, bd, out, V_SZ);
}